// Round 3
// baseline (1960.422 us; speedup 1.0000x reference)
//
#include <hip/hip_runtime.h>

// Problem constants (match reference)
constexpr int NODES = 100000;
constexpr int EDGES = 800000;
constexpr int DIM = 128;       // node dim
constexpr int EDIM = 8;        // edge attr dim
constexpr int HEADS = 8;

// counting-sort scan geometry
constexpr int SCAN_BLK = 512;
constexpr int NSCAN_BLKS = (NODES + SCAN_BLK - 1) / SCAN_BLK;  // 196
constexpr int NPAD = NSCAN_BLKS * SCAN_BLK;                    // 100352

// ---------------------------------------------------------------------------
// Kernel A0: transpose W_node (128x128): Wt[k][d] = W[d][k]
// ---------------------------------------------------------------------------
__global__ __launch_bounds__(256) void transpose_w(const float* __restrict__ W,
                                                   float* __restrict__ Wt) {
    int idx = blockIdx.x * 256 + threadIdx.x;
    int d = idx & 127;
    int k = idx >> 7;
    Wt[k * DIM + d] = W[d * DIM + k];
}

__device__ inline void fma4(float4& a, float s, const float4& w) {
    a.x += s * w.x; a.y += s * w.y; a.z += s * w.z; a.w += s * w.w;
}

// ---------------------------------------------------------------------------
// Kernel A: x_proj = x @ W.T + b.  64 rows/block, 8 rows/thread, 4 cols/thread.
// Wt staged in 16KB quarters (32 k-rows), x tile 32KB. 48KB LDS -> 3 blocks/CU.
// Per k-pair: 2x ds_read_b128 (W) + 8x ds_read_b64 (x, broadcast) feeds 64 FMA.
// ---------------------------------------------------------------------------
__global__ __launch_bounds__(256) void node_proj(const float* __restrict__ x,
                                                 const float* __restrict__ Wt,
                                                 const float* __restrict__ bn,
                                                 float* __restrict__ xp) {
    __shared__ float sWt[32 * DIM];   // 16KB quarter of Wt
    __shared__ float sx[64 * DIM];    // 32KB: 64 node rows

    const int tid = threadIdx.x;
    const int row0 = blockIdx.x * 64;

    // stage x tile (float4, coalesced, guarded for last partial block)
    {
        const float4* x4 = reinterpret_cast<const float4*>(x);
        float4* sx4 = reinterpret_cast<float4*>(sx);
        #pragma unroll
        for (int i = tid; i < 64 * 32; i += 256) {
            int row = row0 + (i >> 5);
            sx4[i] = (row < NODES) ? x4[(size_t)row * 32 + (i & 31)]
                                   : float4{0, 0, 0, 0};
        }
    }

    const int rg = tid >> 5;    // row group 0..7 (owns 8 rows)
    const int dq = tid & 31;    // col quad (owns cols dq*4..dq*4+3)

    float4 acc[8];
    #pragma unroll
    for (int r = 0; r < 8; ++r) acc[r] = float4{0, 0, 0, 0};

    const float4* Wt4 = reinterpret_cast<const float4*>(Wt);
    float4* sWt4 = reinterpret_cast<float4*>(sWt);
    const float2* sx2 = reinterpret_cast<const float2*>(sx);

    #pragma unroll
    for (int q = 0; q < 4; ++q) {
        __syncthreads();   // protect prior-quarter reads (and x staging first pass)
        #pragma unroll
        for (int i = tid; i < 32 * 32; i += 256) sWt4[i] = Wt4[q * 1024 + i];
        __syncthreads();

        const int kb2 = q * 16;   // base in k/2 units
        #pragma unroll
        for (int k2 = 0; k2 < 16; ++k2) {
            float4 w0 = *reinterpret_cast<const float4*>(&sWt[(2 * k2) * DIM + dq * 4]);
            float4 w1 = *reinterpret_cast<const float4*>(&sWt[(2 * k2 + 1) * DIM + dq * 4]);
            #pragma unroll
            for (int r = 0; r < 8; ++r) {
                float2 xv = sx2[(rg * 8 + r) * 64 + kb2 + k2];
                fma4(acc[r], xv.x, w0);
                fma4(acc[r], xv.y, w1);
            }
        }
    }

    float4 b = reinterpret_cast<const float4*>(bn)[dq];
    float4* out4 = reinterpret_cast<float4*>(xp);
    #pragma unroll
    for (int r = 0; r < 8; ++r) {
        int row = row0 + rg * 8 + r;
        if (row < NODES) {
            float4 v = acc[r];
            v.x += b.x; v.y += b.y; v.z += b.z; v.w += b.w;
            out4[(size_t)row * 32 + dq] = v;
        }
    }
}

// ---------------------------------------------------------------------------
// Counting sort of edges by target node
// ---------------------------------------------------------------------------
__global__ __launch_bounds__(256) void hist_kernel(const int* __restrict__ ei,
                                                   int* __restrict__ cnt) {
    int e = blockIdx.x * 256 + threadIdx.x;
    if (e < EDGES) atomicAdd(&cnt[ei[EDGES + e]], 1);
}

__global__ __launch_bounds__(256) void scan_block_sums(const int* __restrict__ cnt,
                                                       int* __restrict__ partial) {
    __shared__ int sd[256];
    int b = blockIdx.x, t = threadIdx.x;
    int s = cnt[b * SCAN_BLK + t] + cnt[b * SCAN_BLK + 256 + t];
    sd[t] = s; __syncthreads();
    for (int d = 128; d > 0; d >>= 1) {
        if (t < d) sd[t] += sd[t + d];
        __syncthreads();
    }
    if (t == 0) partial[b] = sd[0];
}

__global__ __launch_bounds__(256) void scan_partials(int* __restrict__ partial) {
    __shared__ int sd[256];
    int t = threadIdx.x;
    int v = (t < NSCAN_BLKS) ? partial[t] : 0;
    sd[t] = v; __syncthreads();
    for (int d = 1; d < 256; d <<= 1) {
        int u = (t >= d) ? sd[t - d] : 0;
        __syncthreads();
        sd[t] += u;
        __syncthreads();
    }
    if (t < NSCAN_BLKS) partial[t] = sd[t] - v;   // exclusive
}

__global__ __launch_bounds__(256) void scan_write(const int* __restrict__ cnt,
                                                  const int* __restrict__ partial,
                                                  int* __restrict__ start) {
    __shared__ int sd[256];
    int b = blockIdx.x, t = threadIdx.x;
    int i0 = b * SCAN_BLK + 2 * t;
    int c0 = cnt[i0], c1 = cnt[i0 + 1];
    int s = c0 + c1;
    sd[t] = s; __syncthreads();
    for (int d = 1; d < 256; d <<= 1) {
        int u = (t >= d) ? sd[t - d] : 0;
        __syncthreads();
        sd[t] += u;
        __syncthreads();
    }
    int excl = sd[t] - s + partial[b];
    start[i0] = excl;
    start[i0 + 1] = excl + c0;
}

// ---------------------------------------------------------------------------
// Scatter + gate precompute: edge-parallel. For each edge, compute all 8 head
// gates and write (src, gates[8]) at its sorted position. Mutates start so
// start[n] becomes the segment END for node n.
// ---------------------------------------------------------------------------
__global__ __launch_bounds__(256) void scatter_gate(const int* __restrict__ ei,
                                                    const float* __restrict__ ea,
                                                    const float* __restrict__ We,
                                                    const float* __restrict__ be,
                                                    int* __restrict__ start,
                                                    int* __restrict__ srcA,
                                                    float* __restrict__ gateA) {
    __shared__ float sW[HEADS * EDIM];
    __shared__ float sb[HEADS];
    if (threadIdx.x < HEADS * EDIM) sW[threadIdx.x] = We[threadIdx.x];
    if (threadIdx.x < HEADS) sb[threadIdx.x] = be[threadIdx.x];
    __syncthreads();

    int e = blockIdx.x * 256 + threadIdx.x;
    if (e >= EDGES) return;

    int src = ei[e];
    int tgt = ei[EDGES + e];
    int p = atomicAdd(&start[tgt], 1);

    float4 a0 = *reinterpret_cast<const float4*>(ea + (size_t)e * EDIM);
    float4 a1 = *reinterpret_cast<const float4*>(ea + (size_t)e * EDIM + 4);

    float g[HEADS];
    #pragma unroll
    for (int h = 0; h < HEADS; ++h) {
        const float* w = &sW[h * EDIM];
        float z = sb[h]
                + a0.x * w[0] + a0.y * w[1] + a0.z * w[2] + a0.w * w[3]
                + a1.x * w[4] + a1.y * w[5] + a1.z * w[6] + a1.w * w[7];
        g[h] = 1.0f / (1.0f + __expf(-z));
    }

    srcA[p] = src;
    float4* g4 = reinterpret_cast<float4*>(gateA + (size_t)p * HEADS);
    g4[0] = float4{g[0], g[1], g[2], g[3]};
    g4[1] = float4{g[4], g[5], g[6], g[7]};
}

// ---------------------------------------------------------------------------
// Aggregate v2: 32-lane group per node; only ONE random hop (xp[src]).
// srcA/gateA read sequentially (broadcast within group). 4-wide unroll.
// ---------------------------------------------------------------------------
__global__ __launch_bounds__(256) void aggregate_v2(const float* __restrict__ xp,
                                                    const int* __restrict__ startM,
                                                    const int* __restrict__ srcA,
                                                    const float* __restrict__ gateA,
                                                    float* __restrict__ out) {
    const int n = blockIdx.x * 8 + (threadIdx.x >> 5);
    if (n >= NODES) return;
    const int l = threadIdx.x & 31;
    const int h = l >> 2;

    int j = (n == 0) ? 0 : startM[n - 1];
    const int jend = startM[n];

    const float4* xp4 = reinterpret_cast<const float4*>(xp);
    float4 acc = {0, 0, 0, 0};

    for (; j + 4 <= jend; j += 4) {
        int s0 = srcA[j + 0], s1 = srcA[j + 1], s2 = srcA[j + 2], s3 = srcA[j + 3];
        float g0 = gateA[(size_t)(j + 0) * HEADS + h];
        float g1 = gateA[(size_t)(j + 1) * HEADS + h];
        float g2 = gateA[(size_t)(j + 2) * HEADS + h];
        float g3 = gateA[(size_t)(j + 3) * HEADS + h];
        float4 v0 = xp4[(size_t)s0 * 32 + l];
        float4 v1 = xp4[(size_t)s1 * 32 + l];
        float4 v2 = xp4[(size_t)s2 * 32 + l];
        float4 v3 = xp4[(size_t)s3 * 32 + l];
        fma4(acc, g0, v0);
        fma4(acc, g1, v1);
        fma4(acc, g2, v2);
        fma4(acc, g3, v3);
    }
    for (; j < jend; ++j) {
        int s0 = srcA[j];
        float g0 = gateA[(size_t)j * HEADS + h];
        float4 v0 = xp4[(size_t)s0 * 32 + l];
        fma4(acc, g0, v0);
    }

    reinterpret_cast<float4*>(out)[(size_t)n * 32 + l] = acc;
}

// ---------------------------------------------------------------------------
// R1 fallback kernels (mid path): scatter_ids + aggregate (3-hop chain)
// ---------------------------------------------------------------------------
__global__ __launch_bounds__(256) void scatter_ids(const int* __restrict__ ei,
                                                   int* __restrict__ start,
                                                   int* __restrict__ sortedE) {
    int e = blockIdx.x * 256 + threadIdx.x;
    if (e < EDGES) {
        int p = atomicAdd(&start[ei[EDGES + e]], 1);
        sortedE[p] = e;
    }
}

__global__ __launch_bounds__(256) void aggregate(const int* __restrict__ ei,
                                                 const float* __restrict__ ea,
                                                 const float* __restrict__ We,
                                                 const float* __restrict__ be,
                                                 const float* __restrict__ xp,
                                                 const int* __restrict__ startM,
                                                 const int* __restrict__ sortedE,
                                                 float* __restrict__ out) {
    __shared__ float sW[HEADS * EDIM];
    __shared__ float sb[HEADS];
    if (threadIdx.x < HEADS * EDIM) sW[threadIdx.x] = We[threadIdx.x];
    if (threadIdx.x < HEADS) sb[threadIdx.x] = be[threadIdx.x];
    __syncthreads();

    const int n = blockIdx.x * 8 + (threadIdx.x >> 5);
    if (n >= NODES) return;
    const int l = threadIdx.x & 31;
    const int h = l >> 2;

    const float4 wa = *reinterpret_cast<const float4*>(&sW[h * EDIM]);
    const float4 wb = *reinterpret_cast<const float4*>(&sW[h * EDIM + 4]);
    const float bz = sb[h];

    int j = (n == 0) ? 0 : startM[n - 1];
    const int jend = startM[n];
    float4 acc = {0, 0, 0, 0};

    for (; j < jend; ++j) {
        int e0 = sortedE[j];
        int s0 = ei[e0];
        float4 p0 = *reinterpret_cast<const float4*>(ea + (size_t)e0 * EDIM);
        float4 q0 = *reinterpret_cast<const float4*>(ea + (size_t)e0 * EDIM + 4);
        float4 v0 = *reinterpret_cast<const float4*>(xp + (size_t)s0 * DIM + l * 4);
        float z0 = bz + p0.x * wa.x + p0.y * wa.y + p0.z * wa.z + p0.w * wa.w
                      + q0.x * wb.x + q0.y * wb.y + q0.z * wb.z + q0.w * wb.w;
        float g0 = 1.0f / (1.0f + __expf(-z0));
        fma4(acc, g0, v0);
    }

    *reinterpret_cast<float4*>(out + (size_t)n * DIM + l * 4) = acc;
}

// ---------------------------------------------------------------------------
// R0 fallback: per-edge atomic scatter
// ---------------------------------------------------------------------------
__global__ __launch_bounds__(256) void edge_scatter(const int* __restrict__ ei,
                                                    const float* __restrict__ ea,
                                                    const float* __restrict__ We,
                                                    const float* __restrict__ be,
                                                    const float* __restrict__ xp,
                                                    float* __restrict__ out) {
    __shared__ float sW[HEADS * EDIM];
    __shared__ float sb[HEADS];
    if (threadIdx.x < HEADS * EDIM) sW[threadIdx.x] = We[threadIdx.x];
    if (threadIdx.x < HEADS) sb[threadIdx.x] = be[threadIdx.x];
    __syncthreads();

    const int t = blockIdx.x * 256 + threadIdx.x;
    const int e = t >> 5;
    const int l = t & 31;
    if (e >= EDGES) return;

    const int src = ei[e];
    const int tgt = ei[EDGES + e];
    const int h = l >> 2;

    float4 ea0 = *reinterpret_cast<const float4*>(ea + (size_t)e * EDIM);
    float4 ea1 = *reinterpret_cast<const float4*>(ea + (size_t)e * EDIM + 4);
    float4 wa = *reinterpret_cast<const float4*>(&sW[h * EDIM]);
    float4 wb = *reinterpret_cast<const float4*>(&sW[h * EDIM + 4]);
    float z = sb[h]
            + ea0.x * wa.x + ea0.y * wa.y + ea0.z * wa.z + ea0.w * wa.w
            + ea1.x * wb.x + ea1.y * wb.y + ea1.z * wb.z + ea1.w * wb.w;
    float g = 1.0f / (1.0f + __expf(-z));

    float4 v = *reinterpret_cast<const float4*>(xp + (size_t)src * DIM + l * 4);
    float* op = out + (size_t)tgt * DIM + l * 4;
    unsafeAtomicAdd(op + 0, v.x * g);
    unsafeAtomicAdd(op + 1, v.y * g);
    unsafeAtomicAdd(op + 2, v.z * g);
    unsafeAtomicAdd(op + 3, v.w * g);
}

// ---------------------------------------------------------------------------
extern "C" void kernel_launch(void* const* d_in, const int* in_sizes, int n_in,
                              void* d_out, int out_size, void* d_ws, size_t ws_size,
                              hipStream_t stream) {
    const float* x   = (const float*)d_in[0];
    const int*   ei  = (const int*)d_in[1];
    const float* eat = (const float*)d_in[2];
    const float* Wn  = (const float*)d_in[3];
    const float* bn  = (const float*)d_in[4];
    const float* We  = (const float*)d_in[5];
    const float* be  = (const float*)d_in[6];
    float* out = (float*)d_out;

    // workspace layout (shared prefix)
    float* Wt = (float*)d_ws;                               // 16384 f32
    float* xp = Wt + DIM * DIM;                             // NODES*128 f32
    int* cnt     = (int*)(xp + (size_t)NODES * DIM);        // NPAD i32
    int* start   = cnt + NPAD;                              // NPAD i32
    int* partial = start + NPAD;                            // 256 i32
    // new-path tail:
    int* srcA    = partial + 256;                           // EDGES i32
    float* gateA = (float*)(srcA + EDGES);                  // EDGES*8 f32
    // mid-path tail (aliases srcA region):
    int* sortedE = partial + 256;                           // EDGES i32

    const size_t base_elems = (size_t)(DIM * DIM) + (size_t)NODES * DIM
                            + 2 * NPAD + 256;
    const size_t need_new = (base_elems + (size_t)EDGES * 9) * 4;
    const size_t need_mid = (base_elems + (size_t)EDGES) * 4;

    transpose_w<<<64, 256, 0, stream>>>(Wn, Wt);
    node_proj<<<(NODES + 63) / 64, 256, 0, stream>>>(x, Wt, bn, xp);

    if (ws_size >= need_mid) {
        hipMemsetAsync(cnt, 0, (size_t)NPAD * sizeof(int), stream);
        hist_kernel<<<(EDGES + 255) / 256, 256, 0, stream>>>(ei, cnt);
        scan_block_sums<<<NSCAN_BLKS, 256, 0, stream>>>(cnt, partial);
        scan_partials<<<1, 256, 0, stream>>>(partial);
        scan_write<<<NSCAN_BLKS, 256, 0, stream>>>(cnt, partial, start);
        if (ws_size >= need_new) {
            scatter_gate<<<(EDGES + 255) / 256, 256, 0, stream>>>(ei, eat, We, be,
                                                                  start, srcA, gateA);
            aggregate_v2<<<(NODES + 7) / 8, 256, 0, stream>>>(xp, start, srcA,
                                                              gateA, out);
        } else {
            scatter_ids<<<(EDGES + 255) / 256, 256, 0, stream>>>(ei, start, sortedE);
            aggregate<<<(NODES + 7) / 8, 256, 0, stream>>>(ei, eat, We, be, xp,
                                                           start, sortedE, out);
        }
    } else {
        hipMemsetAsync(d_out, 0, (size_t)out_size * sizeof(float), stream);
        edge_scatter<<<(EDGES * 32) / 256, 256, 0, stream>>>(ei, eat, We, be, xp, out);
    }
}

// Round 4
// 158.221 us; speedup vs baseline: 12.3904x; 12.3904x over previous
//
#include <hip/hip_runtime.h>

typedef unsigned short u16;
typedef __attribute__((ext_vector_type(8))) short short8;   // bf16x8 MFMA frag
typedef __attribute__((ext_vector_type(4))) float f32x4;    // MFMA acc frag

// Problem constants (match reference)
constexpr int NODES = 100000;
constexpr int EDGES = 800000;
constexpr int DIM = 128;       // node dim
constexpr int EDIM = 8;        // edge attr dim
constexpr int HEADS = 8;

// counting-sort scan geometry
constexpr int SCAN_BLK = 512;
constexpr int NSCAN_BLKS = (NODES + SCAN_BLK - 1) / SCAN_BLK;  // 196
constexpr int NPAD = NSCAN_BLKS * SCAN_BLK;                    // 100352

__device__ inline u16 f2bf(float f) {              // f32 -> bf16 RNE
    unsigned int u = __float_as_uint(f);
    u = (u + 0x7FFFu + ((u >> 16) & 1u)) >> 16;
    return (u16)u;
}
__device__ inline float bf2f(u16 s) {              // bf16 -> f32 exact
    return __uint_as_float(((unsigned int)s) << 16);
}

// ---------------------------------------------------------------------------
// Convert W_node (128x128 f32, row-major W[n][k]) to bf16 in ws. No transpose:
// the MFMA B-fragment wants B[k][n] = W[n][k], i.e. contiguous k within a row.
// ---------------------------------------------------------------------------
__global__ __launch_bounds__(256) void convert_w(const float* __restrict__ W,
                                                 u16* __restrict__ Wb) {
    int i = blockIdx.x * 256 + threadIdx.x;   // 64 blocks
    Wb[i] = f2bf(W[i]);
}

// ---------------------------------------------------------------------------
// node_proj via MFMA: xp_bf16 = bf16(x @ W.T + b).
// 128 rows/block, 4 waves * 32 rows. W staged in LDS bf16 [128][136] (+8 pad
// -> B-frag ds_read_b128 spreads banks, 2-way max). A-frags from global f32,
// converted in-reg. Per wave: 4 kk * 8 nt * 2 mt = 64 MFMA 16x16x32.
// Frag layout (m89-verified): A row=lane&15, k=(lane>>4)*8+j;
// C/D col=lane&15, row=(lane>>4)*4+reg.
// ---------------------------------------------------------------------------
__global__ __launch_bounds__(256) void node_proj_mfma(const float* __restrict__ x,
                                                      const u16* __restrict__ Wb,
                                                      const float* __restrict__ bn,
                                                      u16* __restrict__ xpb) {
    __shared__ u16 sW[128 * 136];   // 34816 B

    const int tid = threadIdx.x;
    {   // stage W: 128 rows x 16 chunks of 8 bf16 (16B)
        const short8* g = reinterpret_cast<const short8*>(Wb);
        #pragma unroll
        for (int i = tid; i < 128 * 16; i += 256) {
            int row = i >> 4, ch = i & 15;
            *reinterpret_cast<short8*>(&sW[row * 136 + ch * 8]) = g[row * 16 + ch];
        }
    }
    __syncthreads();

    const int w = tid >> 6;        // wave 0..3
    const int l = tid & 63;
    const int lr = l & 15;
    const int lh = l >> 4;
    const int m0 = blockIdx.x * 128 + w * 32;

    f32x4 acc[2][8];
    #pragma unroll
    for (int mt = 0; mt < 2; ++mt)
        #pragma unroll
        for (int nt = 0; nt < 8; ++nt) acc[mt][nt] = f32x4{0, 0, 0, 0};

    #pragma unroll
    for (int kk = 0; kk < 4; ++kk) {
        const int kb = kk * 32 + lh * 8;
        short8 a0, a1;
        {
            int row = m0 + lr;  row = row < NODES ? row : 0;
            const float* p = x + (size_t)row * DIM + kb;
            float4 f0 = *reinterpret_cast<const float4*>(p);
            float4 f1 = *reinterpret_cast<const float4*>(p + 4);
            a0[0]=f2bf(f0.x); a0[1]=f2bf(f0.y); a0[2]=f2bf(f0.z); a0[3]=f2bf(f0.w);
            a0[4]=f2bf(f1.x); a0[5]=f2bf(f1.y); a0[6]=f2bf(f1.z); a0[7]=f2bf(f1.w);
        }
        {
            int row = m0 + 16 + lr;  row = row < NODES ? row : 0;
            const float* p = x + (size_t)row * DIM + kb;
            float4 f0 = *reinterpret_cast<const float4*>(p);
            float4 f1 = *reinterpret_cast<const float4*>(p + 4);
            a1[0]=f2bf(f0.x); a1[1]=f2bf(f0.y); a1[2]=f2bf(f0.z); a1[3]=f2bf(f0.w);
            a1[4]=f2bf(f1.x); a1[5]=f2bf(f1.y); a1[6]=f2bf(f1.z); a1[7]=f2bf(f1.w);
        }
        #pragma unroll
        for (int nt = 0; nt < 8; ++nt) {
            short8 b = *reinterpret_cast<const short8*>(&sW[(nt * 16 + lr) * 136 + kb]);
            acc[0][nt] = __builtin_amdgcn_mfma_f32_16x16x32_bf16(a0, b, acc[0][nt], 0, 0, 0);
            acc[1][nt] = __builtin_amdgcn_mfma_f32_16x16x32_bf16(a1, b, acc[1][nt], 0, 0, 0);
        }
    }

    float bias[8];
    #pragma unroll
    for (int nt = 0; nt < 8; ++nt) bias[nt] = bn[nt * 16 + lr];

    #pragma unroll
    for (int mt = 0; mt < 2; ++mt) {
        #pragma unroll
        for (int r = 0; r < 4; ++r) {
            int grow = m0 + mt * 16 + lh * 4 + r;
            if (grow < NODES) {
                #pragma unroll
                for (int nt = 0; nt < 8; ++nt)
                    xpb[(size_t)grow * DIM + nt * 16 + lr] =
                        f2bf(acc[mt][nt][r] + bias[nt]);
            }
        }
    }
}

// ---------------------------------------------------------------------------
// Counting sort of edges by target node (unchanged, proven)
// ---------------------------------------------------------------------------
__global__ __launch_bounds__(256) void hist_kernel(const int* __restrict__ ei,
                                                   int* __restrict__ cnt) {
    int e = blockIdx.x * 256 + threadIdx.x;
    if (e < EDGES) atomicAdd(&cnt[ei[EDGES + e]], 1);
}

__global__ __launch_bounds__(256) void scan_block_sums(const int* __restrict__ cnt,
                                                       int* __restrict__ partial) {
    __shared__ int sd[256];
    int b = blockIdx.x, t = threadIdx.x;
    int s = cnt[b * SCAN_BLK + t] + cnt[b * SCAN_BLK + 256 + t];
    sd[t] = s; __syncthreads();
    for (int d = 128; d > 0; d >>= 1) {
        if (t < d) sd[t] += sd[t + d];
        __syncthreads();
    }
    if (t == 0) partial[b] = sd[0];
}

__global__ __launch_bounds__(256) void scan_partials(int* __restrict__ partial) {
    __shared__ int sd[256];
    int t = threadIdx.x;
    int v = (t < NSCAN_BLKS) ? partial[t] : 0;
    sd[t] = v; __syncthreads();
    for (int d = 1; d < 256; d <<= 1) {
        int u = (t >= d) ? sd[t - d] : 0;
        __syncthreads();
        sd[t] += u;
        __syncthreads();
    }
    if (t < NSCAN_BLKS) partial[t] = sd[t] - v;   // exclusive
}

__global__ __launch_bounds__(256) void scan_write(const int* __restrict__ cnt,
                                                  const int* __restrict__ partial,
                                                  int* __restrict__ start) {
    __shared__ int sd[256];
    int b = blockIdx.x, t = threadIdx.x;
    int i0 = b * SCAN_BLK + 2 * t;
    int c0 = cnt[i0], c1 = cnt[i0 + 1];
    int s = c0 + c1;
    sd[t] = s; __syncthreads();
    for (int d = 1; d < 256; d <<= 1) {
        int u = (t >= d) ? sd[t - d] : 0;
        __syncthreads();
        sd[t] += u;
        __syncthreads();
    }
    int excl = sd[t] - s + partial[b];
    start[i0] = excl;
    start[i0 + 1] = excl + c0;
}

// ---------------------------------------------------------------------------
// Scatter + gate precompute (unchanged, proven in R3: absmax matched)
// ---------------------------------------------------------------------------
__global__ __launch_bounds__(256) void scatter_gate(const int* __restrict__ ei,
                                                    const float* __restrict__ ea,
                                                    const float* __restrict__ We,
                                                    const float* __restrict__ be,
                                                    int* __restrict__ start,
                                                    int* __restrict__ srcA,
                                                    float* __restrict__ gateA) {
    __shared__ float sW[HEADS * EDIM];
    __shared__ float sb[HEADS];
    if (threadIdx.x < HEADS * EDIM) sW[threadIdx.x] = We[threadIdx.x];
    if (threadIdx.x < HEADS) sb[threadIdx.x] = be[threadIdx.x];
    __syncthreads();

    int e = blockIdx.x * 256 + threadIdx.x;
    if (e >= EDGES) return;

    int src = ei[e];
    int tgt = ei[EDGES + e];
    int p = atomicAdd(&start[tgt], 1);

    float4 a0 = *reinterpret_cast<const float4*>(ea + (size_t)e * EDIM);
    float4 a1 = *reinterpret_cast<const float4*>(ea + (size_t)e * EDIM + 4);

    float g[HEADS];
    #pragma unroll
    for (int h = 0; h < HEADS; ++h) {
        const float* w = &sW[h * EDIM];
        float z = sb[h]
                + a0.x * w[0] + a0.y * w[1] + a0.z * w[2] + a0.w * w[3]
                + a1.x * w[4] + a1.y * w[5] + a1.z * w[6] + a1.w * w[7];
        g[h] = 1.0f / (1.0f + __expf(-z));
    }

    srcA[p] = src;
    float4* g4 = reinterpret_cast<float4*>(gateA + (size_t)p * HEADS);
    g4[0] = float4{g[0], g[1], g[2], g[3]};
    g4[1] = float4{g[4], g[5], g[6], g[7]};
}

// ---------------------------------------------------------------------------
// Aggregate v2 (bf16 gather): 32-lane group per node, lane owns 4 cols (8B).
// One random hop per edge; srcA/gateA sequential.
// ---------------------------------------------------------------------------
__global__ __launch_bounds__(256) void aggregate_v2(const u16* __restrict__ xpb,
                                                    const int* __restrict__ startM,
                                                    const int* __restrict__ srcA,
                                                    const float* __restrict__ gateA,
                                                    float* __restrict__ out) {
    const int n = blockIdx.x * 8 + (threadIdx.x >> 5);
    if (n >= NODES) return;
    const int l = threadIdx.x & 31;
    const int h = l >> 2;

    int j = (n == 0) ? 0 : startM[n - 1];
    const int jend = startM[n];

    float4 acc = {0, 0, 0, 0};

    for (; j + 4 <= jend; j += 4) {
        int s0 = srcA[j + 0], s1 = srcA[j + 1], s2 = srcA[j + 2], s3 = srcA[j + 3];
        float g0 = gateA[(size_t)(j + 0) * HEADS + h];
        float g1 = gateA[(size_t)(j + 1) * HEADS + h];
        float g2 = gateA[(size_t)(j + 2) * HEADS + h];
        float g3 = gateA[(size_t)(j + 3) * HEADS + h];
        ushort4 u0 = *reinterpret_cast<const ushort4*>(xpb + (size_t)s0 * DIM + l * 4);
        ushort4 u1 = *reinterpret_cast<const ushort4*>(xpb + (size_t)s1 * DIM + l * 4);
        ushort4 u2 = *reinterpret_cast<const ushort4*>(xpb + (size_t)s2 * DIM + l * 4);
        ushort4 u3 = *reinterpret_cast<const ushort4*>(xpb + (size_t)s3 * DIM + l * 4);
        acc.x += g0 * bf2f(u0.x); acc.y += g0 * bf2f(u0.y);
        acc.z += g0 * bf2f(u0.z); acc.w += g0 * bf2f(u0.w);
        acc.x += g1 * bf2f(u1.x); acc.y += g1 * bf2f(u1.y);
        acc.z += g1 * bf2f(u1.z); acc.w += g1 * bf2f(u1.w);
        acc.x += g2 * bf2f(u2.x); acc.y += g2 * bf2f(u2.y);
        acc.z += g2 * bf2f(u2.z); acc.w += g2 * bf2f(u2.w);
        acc.x += g3 * bf2f(u3.x); acc.y += g3 * bf2f(u3.y);
        acc.z += g3 * bf2f(u3.z); acc.w += g3 * bf2f(u3.w);
    }
    for (; j < jend; ++j) {
        int s0 = srcA[j];
        float g0 = gateA[(size_t)j * HEADS + h];
        ushort4 u0 = *reinterpret_cast<const ushort4*>(xpb + (size_t)s0 * DIM + l * 4);
        acc.x += g0 * bf2f(u0.x); acc.y += g0 * bf2f(u0.y);
        acc.z += g0 * bf2f(u0.z); acc.w += g0 * bf2f(u0.w);
    }

    reinterpret_cast<float4*>(out)[(size_t)n * 32 + l] = acc;
}

// ---------------------------------------------------------------------------
// Fallback (small ws): per-edge atomic scatter reading bf16 xp
// ---------------------------------------------------------------------------
__global__ __launch_bounds__(256) void edge_scatter(const int* __restrict__ ei,
                                                    const float* __restrict__ ea,
                                                    const float* __restrict__ We,
                                                    const float* __restrict__ be,
                                                    const u16* __restrict__ xpb,
                                                    float* __restrict__ out) {
    __shared__ float sW[HEADS * EDIM];
    __shared__ float sb[HEADS];
    if (threadIdx.x < HEADS * EDIM) sW[threadIdx.x] = We[threadIdx.x];
    if (threadIdx.x < HEADS) sb[threadIdx.x] = be[threadIdx.x];
    __syncthreads();

    const int t = blockIdx.x * 256 + threadIdx.x;
    const int e = t >> 5;
    const int l = t & 31;
    if (e >= EDGES) return;

    const int src = ei[e];
    const int tgt = ei[EDGES + e];
    const int h = l >> 2;

    float4 ea0 = *reinterpret_cast<const float4*>(ea + (size_t)e * EDIM);
    float4 ea1 = *reinterpret_cast<const float4*>(ea + (size_t)e * EDIM + 4);
    float4 wa = *reinterpret_cast<const float4*>(&sW[h * EDIM]);
    float4 wb = *reinterpret_cast<const float4*>(&sW[h * EDIM + 4]);
    float z = sb[h]
            + ea0.x * wa.x + ea0.y * wa.y + ea0.z * wa.z + ea0.w * wa.w
            + ea1.x * wb.x + ea1.y * wb.y + ea1.z * wb.z + ea1.w * wb.w;
    float g = 1.0f / (1.0f + __expf(-z));

    ushort4 u = *reinterpret_cast<const ushort4*>(xpb + (size_t)src * DIM + l * 4);
    float* op = out + (size_t)tgt * DIM + l * 4;
    unsafeAtomicAdd(op + 0, bf2f(u.x) * g);
    unsafeAtomicAdd(op + 1, bf2f(u.y) * g);
    unsafeAtomicAdd(op + 2, bf2f(u.z) * g);
    unsafeAtomicAdd(op + 3, bf2f(u.w) * g);
}

// ---------------------------------------------------------------------------
extern "C" void kernel_launch(void* const* d_in, const int* in_sizes, int n_in,
                              void* d_out, int out_size, void* d_ws, size_t ws_size,
                              hipStream_t stream) {
    const float* x   = (const float*)d_in[0];
    const int*   ei  = (const int*)d_in[1];
    const float* eat = (const float*)d_in[2];
    const float* Wn  = (const float*)d_in[3];
    const float* bn  = (const float*)d_in[4];
    const float* We  = (const float*)d_in[5];
    const float* be  = (const float*)d_in[6];
    float* out = (float*)d_out;

    // workspace layout
    u16* Wb  = (u16*)d_ws;                                  // 16384 bf16 (32KB)
    u16* xpb = Wb + DIM * DIM;                              // NODES*128 bf16 (25.6MB)
    int* cnt     = (int*)(xpb + (size_t)NODES * DIM);       // NPAD i32
    int* start   = cnt + NPAD;                              // NPAD i32
    int* partial = start + NPAD;                            // 256 i32
    int* srcA    = partial + 256;                           // EDGES i32
    float* gateA = (float*)(srcA + EDGES);                  // EDGES*8 f32 (16B-aligned)

    const size_t need = (size_t)(DIM * DIM) * 2 + (size_t)NODES * DIM * 2
                      + (size_t)(2 * NPAD + 256) * 4
                      + (size_t)EDGES * 4 + (size_t)EDGES * HEADS * 4;   // ~55.24 MB

    convert_w<<<64, 256, 0, stream>>>(Wn, Wb);
    node_proj_mfma<<<(NODES + 127) / 128, 256, 0, stream>>>(x, Wb, bn, xpb);

    if (ws_size >= need) {
        hipMemsetAsync(cnt, 0, (size_t)NPAD * sizeof(int), stream);
        hist_kernel<<<(EDGES + 255) / 256, 256, 0, stream>>>(ei, cnt);
        scan_block_sums<<<NSCAN_BLKS, 256, 0, stream>>>(cnt, partial);
        scan_partials<<<1, 256, 0, stream>>>(partial);
        scan_write<<<NSCAN_BLKS, 256, 0, stream>>>(cnt, partial, start);
        scatter_gate<<<(EDGES + 255) / 256, 256, 0, stream>>>(ei, eat, We, be,
                                                              start, srcA, gateA);
        aggregate_v2<<<(NODES + 7) / 8, 256, 0, stream>>>(xpb, start, srcA,
                                                          gateA, out);
    } else {
        hipMemsetAsync(d_out, 0, (size_t)out_size * sizeof(float), stream);
        edge_scatter<<<(EDGES * 32) / 256, 256, 0, stream>>>(ei, eat, We, be, xpb, out);
    }
}